// Round 1
// baseline (817.282 us; speedup 1.0000x reference)
//
#include <hip/hip_runtime.h>

#define BB 8
#define CC 256
#define KK 19
#define HWN 65536
#define H1 2048
#define H2 512
#define NC 38
#define NEG 0.2f

// ---------------- Stage 1: feat[b,k,c] = sum_hw cam[b,k,hw]*x[b,c,hw] / HW ----------------
// grid (64 chunks, 8 batch), block 256 (thread = channel). cam loads are
// wave-uniform (scalar path); x loads are per-lane sequential float4 streams.
__global__ __launch_bounds__(256) void k_feat(const float* __restrict__ x,
                                              const float* __restrict__ cam,
                                              float* __restrict__ feat) {
    const int b = blockIdx.y;
    const int chunk = blockIdx.x;          // 64 chunks of 1024 hw
    const int c = threadIdx.x;             // channel
    const int hw0 = chunk * 1024;

    const float4* __restrict__ xr =
        reinterpret_cast<const float4*>(x + ((size_t)(b * CC + c)) * HWN + hw0);
    const float4* __restrict__ cr =
        reinterpret_cast<const float4*>(cam + (size_t)b * KK * HWN + hw0);

    float acc[KK];
#pragma unroll
    for (int k = 0; k < KK; ++k) acc[k] = 0.f;

#pragma unroll 4
    for (int i = 0; i < 256; ++i) {        // 256 float4 = 1024 hw
        float4 xv = xr[i];
#pragma unroll
        for (int k = 0; k < KK; ++k) {
            float4 cv = cr[(size_t)k * (HWN / 4) + i];   // uniform address -> s_load
            acc[k] += xv.x * cv.x + xv.y * cv.y + xv.z * cv.z + xv.w * cv.w;
        }
    }

    const float s = 1.0f / (float)HWN;
    float* fb = feat + ((size_t)b * KK) * CC + c;
#pragma unroll
    for (int k = 0; k < KK; ++k) atomicAdd(fb + (size_t)k * CC, acc[k] * s);
}

// ---------------- Stage 2a: h1 = lrelu(feat @ W1 + b1)  [152 x 2048] ----------------
// grid (8 colgroups, 19 rowgroups of 8 rows), block 256
__global__ __launch_bounds__(256) void k_mlp1(const float* __restrict__ feat,
                                              const float* __restrict__ W1,
                                              const float* __restrict__ b1,
                                              float* __restrict__ h1) {
    const int j = blockIdx.x * 256 + threadIdx.x;   // 0..2047
    const int r0 = blockIdx.y * 8;                  // 19*8 = 152 rows
    const float4* __restrict__ fv = reinterpret_cast<const float4*>(feat);

    float acc[8];
    const float bias = b1[j];
#pragma unroll
    for (int r = 0; r < 8; ++r) acc[r] = bias;

    for (int c4 = 0; c4 < CC / 4; ++c4) {
        const int c = c4 * 4;
        float w0 = W1[(size_t)(c + 0) * H1 + j];
        float w1 = W1[(size_t)(c + 1) * H1 + j];
        float w2 = W1[(size_t)(c + 2) * H1 + j];
        float w3 = W1[(size_t)(c + 3) * H1 + j];
#pragma unroll
        for (int r = 0; r < 8; ++r) {
            float4 f = fv[(size_t)(r0 + r) * (CC / 4) + c4];  // uniform -> s_load
            acc[r] += f.x * w0 + f.y * w1 + f.z * w2 + f.w * w3;
        }
    }
#pragma unroll
    for (int r = 0; r < 8; ++r) {
        float v = acc[r];
        v = v > 0.f ? v : NEG * v;
        h1[(size_t)(r0 + r) * H1 + j] = v;
    }
}

// ---------------- Stage 2b: h2 = lrelu(h1 @ W2 + b2)  [152 x 512] ----------------
// grid (2 colgroups, 19 rowgroups), block 256
__global__ __launch_bounds__(256) void k_mlp2(const float* __restrict__ h1,
                                              const float* __restrict__ W2,
                                              const float* __restrict__ b2,
                                              float* __restrict__ h2) {
    const int j = blockIdx.x * 256 + threadIdx.x;   // 0..511
    const int r0 = blockIdx.y * 8;
    const float4* __restrict__ hv = reinterpret_cast<const float4*>(h1);

    float acc[8];
    const float bias = b2[j];
#pragma unroll
    for (int r = 0; r < 8; ++r) acc[r] = bias;

    for (int c4 = 0; c4 < H1 / 4; ++c4) {
        const int c = c4 * 4;
        float w0 = W2[(size_t)(c + 0) * H2 + j];
        float w1 = W2[(size_t)(c + 1) * H2 + j];
        float w2 = W2[(size_t)(c + 2) * H2 + j];
        float w3 = W2[(size_t)(c + 3) * H2 + j];
#pragma unroll
        for (int r = 0; r < 8; ++r) {
            float4 f = hv[(size_t)(r0 + r) * (H1 / 4) + c4];  // uniform -> s_load
            acc[r] += f.x * w0 + f.y * w1 + f.z * w2 + f.w * w3;
        }
    }
#pragma unroll
    for (int r = 0; r < 8; ++r) {
        float v = acc[r];
        v = v > 0.f ? v : NEG * v;
        h2[(size_t)(r0 + r) * H2 + j] = v;
    }
}

// ---------------- Stage 3: logits + CE loss + masked reductions ----------------
// grid 8 (one block per sample), block 768 (19*38 = 722 logit threads)
__global__ __launch_bounds__(768) void k_loss(const float* __restrict__ h2,
                                              const float* __restrict__ Wc,
                                              const float* __restrict__ bc,
                                              const int* __restrict__ gt,
                                              const float* __restrict__ gt_src,
                                              const float* __restrict__ gt_tgt,
                                              const float* __restrict__ wts,
                                              float* __restrict__ scal) {
    __shared__ float h2s[KK][H2];
    __shared__ float lg[KK][NC];
    __shared__ float rloss[KK], rmask[KK], rlbl[KK], rmatch[KK];

    const int b = blockIdx.x;
    const int t = threadIdx.x;

    // stage 19 contiguous h2 rows (9728 floats)
    const float* src = h2 + (size_t)b * KK * H2;
    for (int i = t; i < KK * H2; i += 768) ((float*)h2s)[i] = src[i];
    __syncthreads();

    if (t < KK * NC) {
        const int k = t / NC, j = t % NC;
        float acc = bc[j];
        for (int c = 0; c < H2; ++c) acc += h2s[k][c] * Wc[(size_t)c * NC + j];
        lg[k][j] = acc;
    }
    __syncthreads();

    if (t < KK) {
        const int k = t;
        float m = -1e30f; int am = 0;
        for (int j = 0; j < NC; ++j) {
            float v = lg[k][j];
            if (v > m) { m = v; am = j; }        // first max (strict >)
        }
        float se = 0.f, celbl = 0.f, lsum = 0.f, lm = -1e30f; int al = 0;
        for (int j = 0; j < NC; ++j) {
            float v = lg[k][j];
            se += expf(v - m);
            float lb = (j < KK) ? gt_src[((size_t)b * KK + k) * KK + j]
                                : gt_tgt[((size_t)b * KK + k) * KK + (j - KK)];
            celbl += lb * v;
            lsum += lb;
            if (lb > lm) { lm = lb; al = j; }
        }
        float lse = m + logf(se);
        float ce = lse * lsum - celbl;           // -(sum lbl*logp)
        float mask = (gt[b * KK + k] > 0) ? 1.f : 0.f;
        rloss[k]  = mask * wts[b * KK + k] * ce;
        rmask[k]  = mask;
        rlbl[k]   = mask * lsum;
        rmatch[k] = mask * ((am == al) ? 1.f : 0.f);
    }
    __syncthreads();

    if (t == 0) {
        float n = 0.f, sl = 0.f, ls = 0.f, mt = 0.f;
        for (int k = 0; k < KK; ++k) { n += rmask[k]; sl += rloss[k]; ls += rlbl[k]; mt += rmatch[k]; }
        float sample_loss = sl / fmaxf(n, 1.f);
        bool valid = ls > 0.f;
        atomicAdd(&scal[0], valid ? sample_loss : 0.f);
        atomicAdd(&scal[1], valid ? mt : 0.f);
        atomicAdd(&scal[2], valid ? ls : 0.f);
    }
}

__global__ void k_final(const float* __restrict__ scal, float* __restrict__ out) {
    out[0] = scal[0] / (float)BB;
    out[1] = scal[1] / scal[2] * 100.f;
}

extern "C" void kernel_launch(void* const* d_in, const int* in_sizes, int n_in,
                              void* d_out, int out_size, void* d_ws, size_t ws_size,
                              hipStream_t stream) {
    const float* x      = (const float*)d_in[0];
    const float* cam    = (const float*)d_in[1];
    const int*   gt     = (const int*)d_in[2];
    const float* gt_src = (const float*)d_in[3];
    const float* gt_tgt = (const float*)d_in[4];
    const float* wts    = (const float*)d_in[5];
    const float* W1     = (const float*)d_in[6];
    const float* b1     = (const float*)d_in[7];
    const float* W2     = (const float*)d_in[8];
    const float* b2     = (const float*)d_in[9];
    const float* Wc     = (const float*)d_in[10];
    const float* bc     = (const float*)d_in[11];

    float* ws   = (float*)d_ws;
    float* scal = ws;                         // 16 floats (3 used)
    float* feat = ws + 16;                    // 152*256  = 38912
    float* h1   = ws + 16 + 38912;            // 152*2048 = 311296
    float* h2   = ws + 16 + 38912 + 311296;   // 152*512  = 77824

    // zero the accumulated regions (scalars + feat) each call
    hipMemsetAsync(d_ws, 0, (size_t)(16 + 38912) * sizeof(float), stream);

    dim3 g1(64, BB);
    k_feat<<<g1, 256, 0, stream>>>(x, cam, feat);
    dim3 g2(H1 / 256, KK);
    k_mlp1<<<g2, 256, 0, stream>>>(feat, W1, b1, h1);
    dim3 g3(H2 / 256, KK);
    k_mlp2<<<g3, 256, 0, stream>>>(h1, W2, b2, h2);
    k_loss<<<BB, 768, 0, stream>>>(h2, Wc, bc, gt, gt_src, gt_tgt, wts, scal);
    k_final<<<1, 1, 0, stream>>>(scal, (float*)d_out);
}